// Round 2
// baseline (1024.925 us; speedup 1.0000x reference)
//
#include <hip/hip_runtime.h>
#include <math.h>

#define N_NODES   100000
#define N_EDGES   1600000
#define VOCAB     2048
#define NODE_DIM  64
#define HIDDEN    64
#define N_MASK    10000

// ---------------- workspace layout (bytes) ----------------
// h    : [0,          25,600,000)   100000 x 64 f32  (h0, then h1 in place)
// agg  : [25,600,000, 51,200,000)   100000 x 64 f32  (agg1, then agg2 on masked rows)
// deg  : [51,200,000, 51,600,000)   100000 f32
// flag : [51,600,000, 52,000,000)   100000 i32
#define H_OFF    0
#define AGG_OFF  25600000
#define DEG_OFF  51200000
#define FLAG_OFF 51600000

__global__ __launch_bounds__(256) void k_gather_h0(const int* __restrict__ x,
                                                   const float* __restrict__ emb,
                                                   float* __restrict__ h) {
    int tid = blockIdx.x * 256 + threadIdx.x;
    if (tid >= N_NODES * 64) return;
    int n = tid >> 6, f = tid & 63;
    h[tid] = emb[(size_t)x[n] * 64 + f];
}

// one wave per edge: lane j handles feature j. dst/src loads are wave-uniform.
// deg != nullptr  -> also count degree (pass 1)
// flag != nullptr -> skip edges whose dst is unmasked (pass 2); uniform per wave
__global__ __launch_bounds__(256) void k_scatter(const int* __restrict__ src,
                                                 const int* __restrict__ dst,
                                                 const float* __restrict__ h,
                                                 float* __restrict__ agg,
                                                 float* __restrict__ deg,
                                                 const int* __restrict__ flag) {
    int tid = blockIdx.x * 256 + threadIdx.x;   // up to 102.4M < 2^31
    int e = tid >> 6, j = tid & 63;
    if (e >= N_EDGES) return;
    int d = dst[e];
    if (flag != nullptr && flag[d] == 0) return;  // uniform per wave
    if (deg != nullptr && j == 0) atomicAdd(&deg[d], 1.0f);
    int s = src[e];
    atomicAdd(&agg[(size_t)d * 64 + j], h[(size_t)s * 64 + j]);
}

// zero agg rows at masked nodes (so scatter2 accumulates from 0) + set flag
__global__ __launch_bounds__(256) void k_mask_prep(const int* __restrict__ mask,
                                                   float* __restrict__ agg,
                                                   int* __restrict__ flag) {
    int tid = blockIdx.x * 256 + threadIdx.x;
    if (tid >= N_MASK * 64) return;
    int r = tid >> 6, f = tid & 63;
    int n = mask[r];
    agg[(size_t)n * 64 + f] = 0.0f;
    if (f == 0) flag[n] = 1;
}

// C[R][col] = bias[col] + sum_k X[R][k] * W[k][col]
//   X[R][k] = (k<64 ? agg[n][k]/max(deg[n],1) : h[n][k-64]),  n = rowmap?rowmap[R]:R
//   W[k]    = (k<64 ? Wl[k] : Wr[k-64])
// 64x64 tile, 256 threads (16x16 grid of 4x4 micro-tiles), K split in two
// 64-deep stages so LDS = 17,408 + 16,384 = 33,792 B (~4 blocks/CU).
// As[r*68+k]: staging writes consecutive-k -> conflict-free; compute reads
// float4 over k (2-way max, free). Bs[k*64+c]: both sides conflict-free.
__global__ __launch_bounds__(256) void k_gemm(const float* __restrict__ agg,
                                              const float* __restrict__ h,
                                              const float* __restrict__ deg,
                                              const int* __restrict__ rowmap,
                                              const float* __restrict__ Wl,
                                              const float* __restrict__ Wr,
                                              const float* __restrict__ bias,
                                              float* __restrict__ out,
                                              int M, int N, int relu) {
    __shared__ float As[64 * 68];
    __shared__ float Bs[64 * 64];
    const int tid  = threadIdx.x;
    const int row0 = blockIdx.x * 64;
    const int col0 = blockIdx.y * 64;
    const int tc = tid & 15, tr = tid >> 4;

    float acc[4][4];
#pragma unroll
    for (int ci = 0; ci < 4; ci++) {
        float b = bias[col0 + tc * 4 + ci];
#pragma unroll
        for (int ri = 0; ri < 4; ri++) acc[ri][ci] = b;
    }

    for (int half = 0; half < 2; half++) {
        if (half) __syncthreads();   // everyone done reading previous stage
        // ---- stage A (64r x 64k): lane->k coalesced global, conflict-free LDS
#pragma unroll
        for (int i = 0; i < 16; i++) {
            int idx = i * 256 + tid;
            int r = idx >> 6, k = idx & 63;
            int R = row0 + r;
            float v = 0.0f;
            if (R < M) {
                int n = rowmap ? rowmap[R] : R;
                v = (half == 0) ? agg[(size_t)n * 64 + k] * (1.0f / fmaxf(deg[n], 1.0f))
                                : h[(size_t)n * 64 + k];
            }
            As[r * 68 + k] = v;
        }
        // ---- stage B (64k x 64c): lane->c coalesced global, conflict-free LDS
        const float* W = (half == 0) ? Wl : Wr;
#pragma unroll
        for (int i = 0; i < 16; i++) {
            int idx = i * 256 + tid;
            int k = idx >> 6, c = idx & 63;
            Bs[k * 64 + c] = W[(size_t)k * N + col0 + c];
        }
        __syncthreads();

#pragma unroll
        for (int k0 = 0; k0 < 64; k0 += 4) {
            const float4 A0 = *(const float4*)&As[(tr * 4 + 0) * 68 + k0];
            const float4 A1 = *(const float4*)&As[(tr * 4 + 1) * 68 + k0];
            const float4 A2 = *(const float4*)&As[(tr * 4 + 2) * 68 + k0];
            const float4 A3 = *(const float4*)&As[(tr * 4 + 3) * 68 + k0];
            const float4 B0 = *(const float4*)&Bs[(k0 + 0) * 64 + tc * 4];
            const float4 B1 = *(const float4*)&Bs[(k0 + 1) * 64 + tc * 4];
            const float4 B2 = *(const float4*)&Bs[(k0 + 2) * 64 + tc * 4];
            const float4 B3 = *(const float4*)&Bs[(k0 + 3) * 64 + tc * 4];
#define STEP(Aj, Bv)                                                                         \
            acc[0][0] += A0.Aj * Bv.x; acc[0][1] += A0.Aj * Bv.y;                            \
            acc[0][2] += A0.Aj * Bv.z; acc[0][3] += A0.Aj * Bv.w;                            \
            acc[1][0] += A1.Aj * Bv.x; acc[1][1] += A1.Aj * Bv.y;                            \
            acc[1][2] += A1.Aj * Bv.z; acc[1][3] += A1.Aj * Bv.w;                            \
            acc[2][0] += A2.Aj * Bv.x; acc[2][1] += A2.Aj * Bv.y;                            \
            acc[2][2] += A2.Aj * Bv.z; acc[2][3] += A2.Aj * Bv.w;                            \
            acc[3][0] += A3.Aj * Bv.x; acc[3][1] += A3.Aj * Bv.y;                            \
            acc[3][2] += A3.Aj * Bv.z; acc[3][3] += A3.Aj * Bv.w;
            STEP(x, B0)
            STEP(y, B1)
            STEP(z, B2)
            STEP(w, B3)
#undef STEP
        }
    }

#pragma unroll
    for (int ri = 0; ri < 4; ri++) {
        int R = row0 + tr * 4 + ri;
        if (R < M) {
            float4 o;
            o.x = relu ? fmaxf(acc[ri][0], 0.0f) : acc[ri][0];
            o.y = relu ? fmaxf(acc[ri][1], 0.0f) : acc[ri][1];
            o.z = relu ? fmaxf(acc[ri][2], 0.0f) : acc[ri][2];
            o.w = relu ? fmaxf(acc[ri][3], 0.0f) : acc[ri][3];
            *(float4*)&out[(size_t)R * N + col0 + tc * 4] = o;
        }
    }
}

__global__ __launch_bounds__(256) void k_logsoftmax(float* __restrict__ out) {
    const int row = blockIdx.x;
    float* p = out + (size_t)row * VOCAB;
    const int tid = threadIdx.x;
    float v[8];
    float m = -INFINITY;
#pragma unroll
    for (int i = 0; i < 8; i++) { v[i] = p[tid + i * 256]; m = fmaxf(m, v[i]); }
#pragma unroll
    for (int off = 1; off < 64; off <<= 1) m = fmaxf(m, __shfl_xor(m, off));
    __shared__ float redm[4];
    __shared__ float reds[4];
    int wave = tid >> 6;
    if ((tid & 63) == 0) redm[wave] = m;
    __syncthreads();
    m = fmaxf(fmaxf(redm[0], redm[1]), fmaxf(redm[2], redm[3]));
    float s = 0.0f;
#pragma unroll
    for (int i = 0; i < 8; i++) s += expf(v[i] - m);
#pragma unroll
    for (int off = 1; off < 64; off <<= 1) s += __shfl_xor(s, off);
    if ((tid & 63) == 0) reds[wave] = s;
    __syncthreads();
    s = reds[0] + reds[1] + reds[2] + reds[3];
    float L = m + logf(s);
#pragma unroll
    for (int i = 0; i < 8; i++) p[tid + i * 256] = v[i] - L;
}

extern "C" void kernel_launch(void* const* d_in, const int* in_sizes, int n_in,
                              void* d_out, int out_size, void* d_ws, size_t ws_size,
                              hipStream_t stream) {
    const int*   x    = (const int*)d_in[0];
    const int*   ei   = (const int*)d_in[1];
    const int*   src  = ei;
    const int*   dst  = ei + N_EDGES;
    const int*   mask = (const int*)d_in[2];
    const float* emb  = (const float*)d_in[3];
    const float* Wl1  = (const float*)d_in[4];
    const float* bl1  = (const float*)d_in[5];
    const float* Wr1  = (const float*)d_in[6];
    const float* Wl2  = (const float*)d_in[7];
    const float* bl2  = (const float*)d_in[8];
    const float* Wr2  = (const float*)d_in[9];
    float* out = (float*)d_out;

    char* ws = (char*)d_ws;
    float* h    = (float*)(ws + H_OFF);
    float* agg  = (float*)(ws + AGG_OFF);
    float* deg  = (float*)(ws + DEG_OFF);
    int*   flag = (int*)(ws + FLAG_OFF);

    // zero agg + deg + flag in one stream-ordered memset (capture-safe)
    hipMemsetAsync(ws + AGG_OFF, 0, 26400000, stream);

    k_gather_h0<<<(N_NODES * 64 + 255) / 256, 256, 0, stream>>>(x, emb, h);

    // layer-1 aggregation (all nodes) + degree count
    k_scatter<<<(N_EDGES * 64 + 255) / 256, 256, 0, stream>>>(src, dst, h, agg, deg, nullptr);

    // layer 1: h = relu([agg/deg | h] @ [Wl1;Wr1] + b1), in place over h
    dim3 g1((N_NODES + 63) / 64, 1);
    k_gemm<<<g1, 256, 0, stream>>>(agg, h, deg, nullptr, Wl1, Wr1, bl1, h, N_NODES, HIDDEN, 1);

    // layer-2 aggregation restricted to masked destination nodes
    k_mask_prep<<<(N_MASK * 64 + 255) / 256, 256, 0, stream>>>(mask, agg, flag);
    k_scatter<<<(N_EDGES * 64 + 255) / 256, 256, 0, stream>>>(src, dst, h, agg, nullptr, flag);

    // layer 2: logits = [agg/deg | h][mask] @ [Wl2;Wr2] + b2
    dim3 g2((N_MASK + 63) / 64, VOCAB / 64);
    k_gemm<<<g2, 256, 0, stream>>>(agg, h, deg, mask, Wl2, Wr2, bl2, out, N_MASK, VOCAB, 0);

    k_logsoftmax<<<N_MASK, 256, 0, stream>>>(out);
}

// Round 3
// 566.067 us; speedup vs baseline: 1.8106x; 1.8106x over previous
//
#include <hip/hip_runtime.h>
#include <math.h>

#define N_NODES   100000
#define N_EDGES   1600000
#define VOCAB     2048
#define NODE_DIM  64
#define HIDDEN    64
#define N_MASK    10000
#define NB_SCAN   391            // ceil(N_NODES/256)

// ---------------- workspace layout (bytes), all 16-aligned ----------------
#define H1_OFF      0            // 100000*64 f32 = 25,600,000
#define X2_OFF      25600000     // 10000*128 f32 =  5,120,000
#define EWL_OFF     30720000     // 2048*64 f32   =    524,288
#define EWR_OFF     31244288     // 2048*64 f32   =    524,288
#define ROWPTR_OFF  31768576     // 100001 i32    ->   400,016
#define CURSOR_OFF  32168592     // 100000 i32    =    400,000
#define DEGI_OFF    32568592     // 100000 i32    =    400,000
#define BSUM_OFF    32968592     // 512 i32
#define BOFF_OFF    32970640     // 512 i32
#define COLSRC_OFF  32972688     // 1,600,000 i32 =  6,400,000
#define COLVOC_OFF  39372688     // 1,600,000 i32 =  6,400,000
// total ~45.8 MB

// out[v][c] = sum_k emb[v][k] * W[k][c]   (2048x64 @ 64x64)
__global__ __launch_bounds__(256) void k_embw(const float* __restrict__ emb,
                                              const float* __restrict__ W,
                                              float* __restrict__ out) {
    int idx = blockIdx.x * 256 + threadIdx.x;     // 131072 outputs
    int v = idx >> 6, c = idx & 63;               // lanes share v -> emb broadcast, W coalesced
    float s = 0.0f;
#pragma unroll 8
    for (int k = 0; k < 64; k++) s += emb[v * 64 + k] * W[k * 64 + c];
    out[idx] = s;
}

__global__ __launch_bounds__(256) void k_hist(const int* __restrict__ dst,
                                              int* __restrict__ degi) {
    int e = blockIdx.x * 256 + threadIdx.x;
    if (e < N_EDGES) atomicAdd(&degi[dst[e]], 1);
}

__global__ __launch_bounds__(256) void k_scan1(const int* __restrict__ degi,
                                               int* __restrict__ bsum) {
    int i = blockIdx.x * 256 + threadIdx.x;
    int v = (i < N_NODES) ? degi[i] : 0;
#pragma unroll
    for (int off = 1; off < 64; off <<= 1) v += __shfl_xor(v, off);
    __shared__ int ws[4];
    if ((threadIdx.x & 63) == 0) ws[threadIdx.x >> 6] = v;
    __syncthreads();
    if (threadIdx.x == 0) bsum[blockIdx.x] = ws[0] + ws[1] + ws[2] + ws[3];
}

__global__ __launch_bounds__(512) void k_scan2(const int* __restrict__ bsum,
                                               int* __restrict__ boff,
                                               int* __restrict__ rowptr) {
    __shared__ int s[512];
    int t = threadIdx.x;
    int v = (t < NB_SCAN) ? bsum[t] : 0;
    s[t] = v;
    __syncthreads();
    for (int off = 1; off < 512; off <<= 1) {
        int a = (t >= off) ? s[t - off] : 0;
        __syncthreads();
        s[t] += a;
        __syncthreads();
    }
    if (t < NB_SCAN) boff[t] = s[t] - v;          // exclusive
    if (t == NB_SCAN - 1) rowptr[N_NODES] = s[t]; // total = 1.6M
}

__global__ __launch_bounds__(256) void k_scan3(const int* __restrict__ degi,
                                               const int* __restrict__ boff,
                                               int* __restrict__ rowptr,
                                               int* __restrict__ cursor) {
    __shared__ int s[256];
    int t = threadIdx.x;
    int i = blockIdx.x * 256 + t;
    int v = (i < N_NODES) ? degi[i] : 0;
    s[t] = v;
    __syncthreads();
    for (int off = 1; off < 256; off <<= 1) {
        int a = (t >= off) ? s[t - off] : 0;
        __syncthreads();
        s[t] += a;
        __syncthreads();
    }
    if (i < N_NODES) {
        int ex = boff[blockIdx.x] + s[t] - v;
        rowptr[i] = ex;
        cursor[i] = ex;
    }
}

__global__ __launch_bounds__(256) void k_fill(const int* __restrict__ src,
                                              const int* __restrict__ dst,
                                              const int* __restrict__ x,
                                              int* __restrict__ cursor,
                                              int* __restrict__ colsrc,
                                              int* __restrict__ colvoc) {
    int e = blockIdx.x * 256 + threadIdx.x;
    if (e >= N_EDGES) return;
    int pos = atomicAdd(&cursor[dst[e]], 1);
    int s = src[e];
    colsrc[pos] = s;
    colvoc[pos] = x[s];
}

// h1[n] = relu( mean_e embWl[colvoc[e]] + embWr[x[n]] + b1 ), one wave per node
__global__ __launch_bounds__(256) void k_agg1(const int* __restrict__ rowptr,
                                              const int* __restrict__ colvoc,
                                              const int* __restrict__ x,
                                              const float* __restrict__ embWl,
                                              const float* __restrict__ embWr,
                                              const float* __restrict__ b1,
                                              float* __restrict__ h1) {
    int gw = (blockIdx.x * 256 + threadIdx.x) >> 6;
    int j = threadIdx.x & 63;
    if (gw >= N_NODES) return;
    int r0 = rowptr[gw], r1 = rowptr[gw + 1];
    float sum = 0.0f;
    for (int e = r0; e < r1; e++) sum += embWl[(colvoc[e] << 6) + j];
    float inv = 1.0f / fmaxf((float)(r1 - r0), 1.0f);
    float self = embWr[(x[gw] << 6) + j];
    h1[(gw << 6) + j] = fmaxf(sum * inv + self + b1[j], 0.0f);
}

// X2[m] = [ mean_e h1[colsrc[e]] | h1[mask[m]] ], one wave per masked row
__global__ __launch_bounds__(256) void k_x2(const int* __restrict__ mask,
                                            const int* __restrict__ rowptr,
                                            const int* __restrict__ colsrc,
                                            const float* __restrict__ h1,
                                            float* __restrict__ X2) {
    int gw = (blockIdx.x * 256 + threadIdx.x) >> 6;
    int j = threadIdx.x & 63;
    if (gw >= N_MASK) return;
    int n = mask[gw];
    int r0 = rowptr[n], r1 = rowptr[n + 1];
    float sum = 0.0f;
    for (int e = r0; e < r1; e++) sum += h1[(colsrc[e] << 6) + j];
    float inv = 1.0f / fmaxf((float)(r1 - r0), 1.0f);
    X2[gw * 128 + j] = sum * inv;
    X2[gw * 128 + 64 + j] = h1[(n << 6) + j];
}

// out[R][col] = b2[col] + sum_k X2[R][k] * W2[k][col],  W2 = [Wl2;Wr2]
// 64x64 tile, 256 threads, 4x4 micro-tiles, K=128 in two 64-deep stages.
__global__ __launch_bounds__(256) void k_gemm2(const float* __restrict__ X2,
                                               const float* __restrict__ Wl,
                                               const float* __restrict__ Wr,
                                               const float* __restrict__ bias,
                                               float* __restrict__ out,
                                               int M, int N) {
    __shared__ float As[64 * 68];
    __shared__ float Bs[64 * 64];
    const int tid  = threadIdx.x;
    const int row0 = blockIdx.x * 64;
    const int col0 = blockIdx.y * 64;
    const int tc = tid & 15, tr = tid >> 4;

    float acc[4][4];
#pragma unroll
    for (int ci = 0; ci < 4; ci++) {
        float b = bias[col0 + tc * 4 + ci];
#pragma unroll
        for (int ri = 0; ri < 4; ri++) acc[ri][ci] = b;
    }

    for (int half = 0; half < 2; half++) {
        if (half) __syncthreads();
#pragma unroll
        for (int i = 0; i < 16; i++) {
            int idx = i * 256 + tid;
            int r = idx >> 6, k = idx & 63;
            int R = row0 + r;
            As[r * 68 + k] = (R < M) ? X2[(size_t)R * 128 + half * 64 + k] : 0.0f;
        }
        const float* W = half ? Wr : Wl;
#pragma unroll
        for (int i = 0; i < 16; i++) {
            int idx = i * 256 + tid;
            int k = idx >> 6, c = idx & 63;
            Bs[k * 64 + c] = W[(size_t)k * N + col0 + c];
        }
        __syncthreads();

#pragma unroll
        for (int k0 = 0; k0 < 64; k0 += 4) {
            const float4 A0 = *(const float4*)&As[(tr * 4 + 0) * 68 + k0];
            const float4 A1 = *(const float4*)&As[(tr * 4 + 1) * 68 + k0];
            const float4 A2 = *(const float4*)&As[(tr * 4 + 2) * 68 + k0];
            const float4 A3 = *(const float4*)&As[(tr * 4 + 3) * 68 + k0];
            const float4 B0 = *(const float4*)&Bs[(k0 + 0) * 64 + tc * 4];
            const float4 B1 = *(const float4*)&Bs[(k0 + 1) * 64 + tc * 4];
            const float4 B2 = *(const float4*)&Bs[(k0 + 2) * 64 + tc * 4];
            const float4 B3 = *(const float4*)&Bs[(k0 + 3) * 64 + tc * 4];
#define STEP(Aj, Bv)                                                          \
            acc[0][0] += A0.Aj * Bv.x; acc[0][1] += A0.Aj * Bv.y;             \
            acc[0][2] += A0.Aj * Bv.z; acc[0][3] += A0.Aj * Bv.w;             \
            acc[1][0] += A1.Aj * Bv.x; acc[1][1] += A1.Aj * Bv.y;             \
            acc[1][2] += A1.Aj * Bv.z; acc[1][3] += A1.Aj * Bv.w;             \
            acc[2][0] += A2.Aj * Bv.x; acc[2][1] += A2.Aj * Bv.y;             \
            acc[2][2] += A2.Aj * Bv.z; acc[2][3] += A2.Aj * Bv.w;             \
            acc[3][0] += A3.Aj * Bv.x; acc[3][1] += A3.Aj * Bv.y;             \
            acc[3][2] += A3.Aj * Bv.z; acc[3][3] += A3.Aj * Bv.w;
            STEP(x, B0)
            STEP(y, B1)
            STEP(z, B2)
            STEP(w, B3)
#undef STEP
        }
    }

#pragma unroll
    for (int ri = 0; ri < 4; ri++) {
        int R = row0 + tr * 4 + ri;
        if (R < M)
            *(float4*)&out[(size_t)R * N + col0 + tc * 4] =
                *(const float4*)&acc[ri][0];
    }
}

__global__ __launch_bounds__(256) void k_logsoftmax(float* __restrict__ out) {
    const int row = blockIdx.x;
    float* p = out + (size_t)row * VOCAB;
    const int tid = threadIdx.x;
    float v[8];
    float m = -INFINITY;
#pragma unroll
    for (int i = 0; i < 8; i++) { v[i] = p[tid + i * 256]; m = fmaxf(m, v[i]); }
#pragma unroll
    for (int off = 1; off < 64; off <<= 1) m = fmaxf(m, __shfl_xor(m, off));
    __shared__ float redm[4];
    __shared__ float reds[4];
    int wave = tid >> 6;
    if ((tid & 63) == 0) redm[wave] = m;
    __syncthreads();
    m = fmaxf(fmaxf(redm[0], redm[1]), fmaxf(redm[2], redm[3]));
    float s = 0.0f;
#pragma unroll
    for (int i = 0; i < 8; i++) s += expf(v[i] - m);
#pragma unroll
    for (int off = 1; off < 64; off <<= 1) s += __shfl_xor(s, off);
    if ((tid & 63) == 0) reds[wave] = s;
    __syncthreads();
    s = reds[0] + reds[1] + reds[2] + reds[3];
    float L = m + logf(s);
#pragma unroll
    for (int i = 0; i < 8; i++) p[tid + i * 256] = v[i] - L;
}

extern "C" void kernel_launch(void* const* d_in, const int* in_sizes, int n_in,
                              void* d_out, int out_size, void* d_ws, size_t ws_size,
                              hipStream_t stream) {
    const int*   x    = (const int*)d_in[0];
    const int*   ei   = (const int*)d_in[1];
    const int*   src  = ei;
    const int*   dst  = ei + N_EDGES;
    const int*   mask = (const int*)d_in[2];
    const float* emb  = (const float*)d_in[3];
    const float* Wl1  = (const float*)d_in[4];
    const float* bl1  = (const float*)d_in[5];
    const float* Wr1  = (const float*)d_in[6];
    const float* Wl2  = (const float*)d_in[7];
    const float* bl2  = (const float*)d_in[8];
    const float* Wr2  = (const float*)d_in[9];
    float* out = (float*)d_out;

    char* ws = (char*)d_ws;
    float* h1     = (float*)(ws + H1_OFF);
    float* X2     = (float*)(ws + X2_OFF);
    float* embWl  = (float*)(ws + EWL_OFF);
    float* embWr  = (float*)(ws + EWR_OFF);
    int*   rowptr = (int*)(ws + ROWPTR_OFF);
    int*   cursor = (int*)(ws + CURSOR_OFF);
    int*   degi   = (int*)(ws + DEGI_OFF);
    int*   bsum   = (int*)(ws + BSUM_OFF);
    int*   boff   = (int*)(ws + BOFF_OFF);
    int*   colsrc = (int*)(ws + COLSRC_OFF);
    int*   colvoc = (int*)(ws + COLVOC_OFF);

    hipMemsetAsync(ws + DEGI_OFF, 0, 400000, stream);   // only degi needs zeros

    // tiny transformed-embedding tables (L2-resident thereafter)
    k_embw<<<512, 256, 0, stream>>>(emb, Wl1, embWl);
    k_embw<<<512, 256, 0, stream>>>(emb, Wr1, embWr);

    // CSR by destination
    k_hist <<<(N_EDGES + 255) / 256, 256, 0, stream>>>(dst, degi);
    k_scan1<<<NB_SCAN, 256, 0, stream>>>(degi, bsum);
    k_scan2<<<1, 512, 0, stream>>>(bsum, boff, rowptr);
    k_scan3<<<NB_SCAN, 256, 0, stream>>>(degi, boff, rowptr, cursor);
    k_fill <<<(N_EDGES + 255) / 256, 256, 0, stream>>>(src, dst, x, cursor, colsrc, colvoc);

    // layer 1 fused: aggregate transformed embeddings + self + bias + relu
    k_agg1<<<(N_NODES * 64 + 255) / 256, 256, 0, stream>>>(rowptr, colvoc, x, embWl, embWr, bl1, h1);

    // layer 2: gather masked rows into compact X2, then GEMM
    k_x2<<<(N_MASK * 64 + 255) / 256, 256, 0, stream>>>(mask, rowptr, colsrc, h1, X2);
    dim3 g2((N_MASK + 63) / 64, VOCAB / 64);
    k_gemm2<<<g2, 256, 0, stream>>>(X2, Wl2, Wr2, bl2, out, N_MASK, VOCAB);

    k_logsoftmax<<<N_MASK, 256, 0, stream>>>(out);
}

// Round 4
// 456.823 us; speedup vs baseline: 2.2436x; 1.2391x over previous
//
#include <hip/hip_runtime.h>
#include <math.h>

#define N_NODES   100000
#define N_EDGES   1600000
#define VOCAB     2048
#define NODE_DIM  64
#define HIDDEN    64
#define N_MASK    10000
#define NB_SCAN   391            // ceil(N_NODES/256)

typedef __attribute__((ext_vector_type(8))) short short8;
typedef __attribute__((ext_vector_type(4))) float f32x4;
typedef unsigned short ushort_t;
typedef unsigned int uint_t;

// ---------------- workspace layout (bytes), all 16-aligned ----------------
#define H1_OFF      0            // 100000*64 f32 = 25,600,000
#define X2B_OFF     25600000     // 10000*128 bf16 = 2,560,000
#define W2T_OFF     28160000     // 2048*128 bf16  =   524,288
#define EWL_OFF     28684288     // 2048*64 f32    =   524,288
#define EWR_OFF     29208576     // 2048*64 f32    =   524,288
#define ROWPTR_OFF  29732864     // 100001 i32
#define CURSOR_OFF  30132880     // 100000 i32
#define DEGI_OFF    30532880     // 100000 i32
#define BSUM_OFF    30932880     // 512 i32
#define BOFF_OFF    30934928     // 512 i32
#define COLSRC_OFF  30936976     // 1,600,000 i32 = 6,400,000
#define COLVOC_OFF  37336976     // 1,600,000 i32 = 6,400,000
// total ~43.7 MB

__device__ __forceinline__ ushort_t f2bf(float f) {
    uint_t u = __builtin_bit_cast(uint_t, f);
    u += 0x7FFFu + ((u >> 16) & 1u);        // round-to-nearest-even
    return (ushort_t)(u >> 16);
}

// out[v][c] = sum_k emb[v][k] * W[k][c]   (2048x64 @ 64x64)
__global__ __launch_bounds__(256) void k_embw(const float* __restrict__ emb,
                                              const float* __restrict__ W,
                                              float* __restrict__ out) {
    int idx = blockIdx.x * 256 + threadIdx.x;     // 131072 outputs
    int v = idx >> 6, c = idx & 63;               // lanes share v -> emb broadcast, W coalesced
    float s = 0.0f;
#pragma unroll 8
    for (int k = 0; k < 64; k++) s += emb[v * 64 + k] * W[k * 64 + c];
    out[idx] = s;
}

// W2T[n][k] = bf16( k<64 ? Wl2[k][n] : Wr2[k-64][n] ),  [2048][128]
// LDS-tiled transpose: coalesced reads, coalesced (2B) writes.
__global__ __launch_bounds__(256) void k_w2t(const float* __restrict__ Wl2,
                                             const float* __restrict__ Wr2,
                                             ushort_t* __restrict__ W2T) {
    __shared__ ushort_t T[64 * 66];
    const int k0 = blockIdx.x * 64;               // 0 or 64
    const int n0 = blockIdx.y * 64;
    const float* Wsrc = (k0 == 0) ? Wl2 : Wr2;
    const int tid = threadIdx.x;
#pragma unroll
    for (int i = 0; i < 16; i++) {
        int idx = i * 256 + tid;
        int k = idx >> 6, n = idx & 63;           // lane -> n : coalesced global read
        T[n * 66 + k] = f2bf(Wsrc[(size_t)k * VOCAB + n0 + n]);
    }
    __syncthreads();
#pragma unroll
    for (int i = 0; i < 16; i++) {
        int idx = i * 256 + tid;
        int n = idx >> 6, k = idx & 63;           // lane -> k : coalesced global write
        W2T[(size_t)(n0 + n) * 128 + k0 + k] = T[n * 66 + k];
    }
}

__global__ __launch_bounds__(256) void k_hist(const int* __restrict__ dst,
                                              int* __restrict__ degi) {
    int e = blockIdx.x * 256 + threadIdx.x;
    if (e < N_EDGES) atomicAdd(&degi[dst[e]], 1);
}

__global__ __launch_bounds__(256) void k_scan1(const int* __restrict__ degi,
                                               int* __restrict__ bsum) {
    int i = blockIdx.x * 256 + threadIdx.x;
    int v = (i < N_NODES) ? degi[i] : 0;
#pragma unroll
    for (int off = 1; off < 64; off <<= 1) v += __shfl_xor(v, off);
    __shared__ int ws[4];
    if ((threadIdx.x & 63) == 0) ws[threadIdx.x >> 6] = v;
    __syncthreads();
    if (threadIdx.x == 0) bsum[blockIdx.x] = ws[0] + ws[1] + ws[2] + ws[3];
}

__global__ __launch_bounds__(512) void k_scan2(const int* __restrict__ bsum,
                                               int* __restrict__ boff,
                                               int* __restrict__ rowptr) {
    __shared__ int s[512];
    int t = threadIdx.x;
    int v = (t < NB_SCAN) ? bsum[t] : 0;
    s[t] = v;
    __syncthreads();
    for (int off = 1; off < 512; off <<= 1) {
        int a = (t >= off) ? s[t - off] : 0;
        __syncthreads();
        s[t] += a;
        __syncthreads();
    }
    if (t < NB_SCAN) boff[t] = s[t] - v;          // exclusive
    if (t == NB_SCAN - 1) rowptr[N_NODES] = s[t]; // total = 1.6M
}

__global__ __launch_bounds__(256) void k_scan3(const int* __restrict__ degi,
                                               const int* __restrict__ boff,
                                               int* __restrict__ rowptr,
                                               int* __restrict__ cursor) {
    __shared__ int s[256];
    int t = threadIdx.x;
    int i = blockIdx.x * 256 + t;
    int v = (i < N_NODES) ? degi[i] : 0;
    s[t] = v;
    __syncthreads();
    for (int off = 1; off < 256; off <<= 1) {
        int a = (t >= off) ? s[t - off] : 0;
        __syncthreads();
        s[t] += a;
        __syncthreads();
    }
    if (i < N_NODES) {
        int ex = boff[blockIdx.x] + s[t] - v;
        rowptr[i] = ex;
        cursor[i] = ex;
    }
}

__global__ __launch_bounds__(256) void k_fill(const int* __restrict__ src,
                                              const int* __restrict__ dst,
                                              const int* __restrict__ x,
                                              int* __restrict__ cursor,
                                              int* __restrict__ colsrc,
                                              int* __restrict__ colvoc) {
    int e = blockIdx.x * 256 + threadIdx.x;
    if (e >= N_EDGES) return;
    int pos = atomicAdd(&cursor[dst[e]], 1);
    int s = src[e];
    colsrc[pos] = s;
    colvoc[pos] = x[s];
}

// h1[n] = relu( mean_e embWl[colvoc[e]] + embWr[x[n]] + b1 ), one wave per node
__global__ __launch_bounds__(256) void k_agg1(const int* __restrict__ rowptr,
                                              const int* __restrict__ colvoc,
                                              const int* __restrict__ x,
                                              const float* __restrict__ embWl,
                                              const float* __restrict__ embWr,
                                              const float* __restrict__ b1,
                                              float* __restrict__ h1) {
    int gw = (blockIdx.x * 256 + threadIdx.x) >> 6;
    int j = threadIdx.x & 63;
    if (gw >= N_NODES) return;
    int r0 = rowptr[gw], r1 = rowptr[gw + 1];
    float sum = 0.0f;
    for (int e = r0; e < r1; e++) sum += embWl[(colvoc[e] << 6) + j];
    float inv = 1.0f / fmaxf((float)(r1 - r0), 1.0f);
    float self = embWr[(x[gw] << 6) + j];
    h1[(gw << 6) + j] = fmaxf(sum * inv + self + b1[j], 0.0f);
}

// X2b[m] = bf16[ mean_e h1[colsrc[e]] | h1[mask[m]] ], one wave per masked row
__global__ __launch_bounds__(256) void k_x2(const int* __restrict__ mask,
                                            const int* __restrict__ rowptr,
                                            const int* __restrict__ colsrc,
                                            const float* __restrict__ h1,
                                            ushort_t* __restrict__ X2b) {
    int gw = (blockIdx.x * 256 + threadIdx.x) >> 6;
    int j = threadIdx.x & 63;
    if (gw >= N_MASK) return;
    int n = mask[gw];
    int r0 = rowptr[n], r1 = rowptr[n + 1];
    float sum = 0.0f;
    for (int e = r0; e < r1; e++) sum += h1[(colsrc[e] << 6) + j];
    float inv = 1.0f / fmaxf((float)(r1 - r0), 1.0f);
    X2b[gw * 128 + j]      = f2bf(sum * inv);
    X2b[gw * 128 + 64 + j] = f2bf(h1[(n << 6) + j]);
}

// out[R][c] = b2[c] + X2[R] . W2T[c]   via bf16 MFMA, fp32 accumulate.
// 64x64 tile / block, 4 waves, each wave one 32x32 quadrant (2x2 MFMA tiles).
// LDS rows padded to 144 bf16 (288 B): frag reads 16B-aligned, 8 acc/bank (min).
__global__ __launch_bounds__(256) void k_gemm2_mfma(const ushort_t* __restrict__ X2b,
                                                    const ushort_t* __restrict__ W2T,
                                                    const float* __restrict__ bias,
                                                    float* __restrict__ out,
                                                    int M) {
    __shared__ ushort_t As[64 * 144];
    __shared__ ushort_t Bs[64 * 144];
    const int tid  = threadIdx.x;
    const int row0 = blockIdx.x * 64;
    const int col0 = blockIdx.y * 64;

    // stage A: 64 rows x 128 bf16, 16B chunks, coalesced; zero-pad rows >= M
#pragma unroll
    for (int i = 0; i < 4; i++) {
        int idx = i * 256 + tid;
        int r = idx >> 4, ch = idx & 15;
        int R = row0 + r;
        short8 v = {0, 0, 0, 0, 0, 0, 0, 0};
        if (R < M) v = *(const short8*)(X2b + (size_t)R * 128 + ch * 8);
        *(short8*)(As + r * 144 + ch * 8) = v;
    }
    // stage B: 64 cols (rows of W2T) x 128 bf16
#pragma unroll
    for (int i = 0; i < 4; i++) {
        int idx = i * 256 + tid;
        int r = idx >> 4, ch = idx & 15;
        *(short8*)(Bs + r * 144 + ch * 8) =
            *(const short8*)(W2T + (size_t)(col0 + r) * 128 + ch * 8);
    }
    __syncthreads();

    const int lane = tid & 63;
    const int wv   = tid >> 6;            // 4 waves
    const int wr = wv >> 1, wc = wv & 1;  // 2x2 wave grid of 32x32 quadrants
    const int l15 = lane & 15, q = lane >> 4;

    f32x4 acc[2][2] = {};
    const ushort_t* Abase = As + (wr * 32 + l15) * 144 + q * 8;
    const ushort_t* Bbase = Bs + (wc * 32 + l15) * 144 + q * 8;

#pragma unroll
    for (int ks = 0; ks < 4; ks++) {
        short8 a0 = *(const short8*)(Abase + ks * 32);
        short8 a1 = *(const short8*)(Abase + 16 * 144 + ks * 32);
        short8 b0 = *(const short8*)(Bbase + ks * 32);
        short8 b1 = *(const short8*)(Bbase + 16 * 144 + ks * 32);
        acc[0][0] = __builtin_amdgcn_mfma_f32_16x16x32_bf16(a0, b0, acc[0][0], 0, 0, 0);
        acc[0][1] = __builtin_amdgcn_mfma_f32_16x16x32_bf16(a0, b1, acc[0][1], 0, 0, 0);
        acc[1][0] = __builtin_amdgcn_mfma_f32_16x16x32_bf16(a1, b0, acc[1][0], 0, 0, 0);
        acc[1][1] = __builtin_amdgcn_mfma_f32_16x16x32_bf16(a1, b1, acc[1][1], 0, 0, 0);
    }

    // C/D layout: col = lane&15, row = (lane>>4)*4 + reg  [verified m89/m91]
#pragma unroll
    for (int ni = 0; ni < 2; ni++) {
        int c_ = col0 + wc * 32 + ni * 16 + l15;
        float bv = bias[c_];
#pragma unroll
        for (int mi = 0; mi < 2; mi++) {
#pragma unroll
            for (int reg = 0; reg < 4; reg++) {
                int r_ = row0 + wr * 32 + mi * 16 + q * 4 + reg;
                if (r_ < M) out[(size_t)r_ * VOCAB + c_] = acc[mi][ni][reg] + bv;
            }
        }
    }
}

__global__ __launch_bounds__(256) void k_logsoftmax(float* __restrict__ out) {
    const int row = blockIdx.x;
    float* p = out + (size_t)row * VOCAB;
    const int tid = threadIdx.x;
    float v[8];
    float m = -INFINITY;
#pragma unroll
    for (int i = 0; i < 8; i++) { v[i] = p[tid + i * 256]; m = fmaxf(m, v[i]); }
#pragma unroll
    for (int off = 1; off < 64; off <<= 1) m = fmaxf(m, __shfl_xor(m, off));
    __shared__ float redm[4];
    __shared__ float reds[4];
    int wave = tid >> 6;
    if ((tid & 63) == 0) redm[wave] = m;
    __syncthreads();
    m = fmaxf(fmaxf(redm[0], redm[1]), fmaxf(redm[2], redm[3]));
    float s = 0.0f;
#pragma unroll
    for (int i = 0; i < 8; i++) s += expf(v[i] - m);
#pragma unroll
    for (int off = 1; off < 64; off <<= 1) s += __shfl_xor(s, off);
    if ((tid & 63) == 0) reds[wave] = s;
    __syncthreads();
    s = reds[0] + reds[1] + reds[2] + reds[3];
    float L = m + logf(s);
#pragma unroll
    for (int i = 0; i < 8; i++) p[tid + i * 256] = v[i] - L;
}

extern "C" void kernel_launch(void* const* d_in, const int* in_sizes, int n_in,
                              void* d_out, int out_size, void* d_ws, size_t ws_size,
                              hipStream_t stream) {
    const int*   x    = (const int*)d_in[0];
    const int*   ei   = (const int*)d_in[1];
    const int*   src  = ei;
    const int*   dst  = ei + N_EDGES;
    const int*   mask = (const int*)d_in[2];
    const float* emb  = (const float*)d_in[3];
    const float* Wl1  = (const float*)d_in[4];
    const float* bl1  = (const float*)d_in[5];
    const float* Wr1  = (const float*)d_in[6];
    const float* Wl2  = (const float*)d_in[7];
    const float* bl2  = (const float*)d_in[8];
    const float* Wr2  = (const float*)d_in[9];
    float* out = (float*)d_out;

    char* ws = (char*)d_ws;
    float*    h1     = (float*)(ws + H1_OFF);
    ushort_t* X2b    = (ushort_t*)(ws + X2B_OFF);
    ushort_t* W2T    = (ushort_t*)(ws + W2T_OFF);
    float*    embWl  = (float*)(ws + EWL_OFF);
    float*    embWr  = (float*)(ws + EWR_OFF);
    int*      rowptr = (int*)(ws + ROWPTR_OFF);
    int*      cursor = (int*)(ws + CURSOR_OFF);
    int*      degi   = (int*)(ws + DEGI_OFF);
    int*      bsum   = (int*)(ws + BSUM_OFF);
    int*      boff   = (int*)(ws + BOFF_OFF);
    int*      colsrc = (int*)(ws + COLSRC_OFF);
    int*      colvoc = (int*)(ws + COLVOC_OFF);

    hipMemsetAsync(ws + DEGI_OFF, 0, 400000, stream);   // only degi needs zeros

    // tiny transformed-embedding tables + bf16-transposed layer-2 weights
    k_embw<<<512, 256, 0, stream>>>(emb, Wl1, embWl);
    k_embw<<<512, 256, 0, stream>>>(emb, Wr1, embWr);
    dim3 gw2(2, VOCAB / 64);
    k_w2t<<<gw2, 256, 0, stream>>>(Wl2, Wr2, W2T);

    // CSR by destination
    k_hist <<<(N_EDGES + 255) / 256, 256, 0, stream>>>(dst, degi);
    k_scan1<<<NB_SCAN, 256, 0, stream>>>(degi, bsum);
    k_scan2<<<1, 512, 0, stream>>>(bsum, boff, rowptr);
    k_scan3<<<NB_SCAN, 256, 0, stream>>>(degi, boff, rowptr, cursor);
    k_fill <<<(N_EDGES + 255) / 256, 256, 0, stream>>>(src, dst, x, cursor, colsrc, colvoc);

    // layer 1 fused: aggregate transformed embeddings + self + bias + relu
    k_agg1<<<(N_NODES * 64 + 255) / 256, 256, 0, stream>>>(rowptr, colvoc, x, embWl, embWr, bl1, h1);

    // layer 2: gather masked rows into compact bf16 X2, then MFMA GEMM
    k_x2<<<(N_MASK * 64 + 255) / 256, 256, 0, stream>>>(mask, rowptr, colsrc, h1, X2b);
    dim3 g2((N_MASK + 63) / 64, VOCAB / 64);
    k_gemm2_mfma<<<g2, 256, 0, stream>>>(X2b, W2T, bl2, out, N_MASK);

    k_logsoftmax<<<N_MASK, 256, 0, stream>>>(out);
}

// Round 5
// 416.476 us; speedup vs baseline: 2.4609x; 1.0969x over previous
//
#include <hip/hip_runtime.h>
#include <math.h>

#define N_NODES   100000
#define N_EDGES   1600000
#define VOCAB     2048
#define NODE_DIM  64
#define HIDDEN    64
#define N_MASK    10000
#define NB_SCAN   391            // ceil(N_NODES/256)

typedef __attribute__((ext_vector_type(8))) short short8;
typedef __attribute__((ext_vector_type(4))) float f32x4;
typedef unsigned short ushort_t;
typedef unsigned int uint_t;

// ---------------- workspace layout (bytes), all 16-aligned ----------------
#define H1_OFF      0            // 100000*64 f32 = 25,600,000
#define X2B_OFF     25600000     // 10000*128 bf16 = 2,560,000
#define W2T_OFF     28160000     // 2048*128 bf16  =   524,288
#define EWL_OFF     28684288     // 2048*64 f32    =   524,288
#define EWR_OFF     29208576     // 2048*64 f32    =   524,288
#define ROWPTR_OFF  29732864     // 100001 i32
#define CURSOR_OFF  30132880     // 100000 i32
#define DEGI_OFF    30532880     // 100000 i32
#define BSUM_OFF    30932880     // 512 i32
#define BOFF_OFF    30934928     // 512 i32
#define COL2_OFF    30936976     // 1,600,000 int2 = 12,800,000  (8B aligned)
// total ~43.7 MB

__device__ __forceinline__ ushort_t f2bf(float f) {
    uint_t u = __builtin_bit_cast(uint_t, f);
    u += 0x7FFFu + ((u >> 16) & 1u);        // round-to-nearest-even
    return (ushort_t)(u >> 16);
}

// both transformed-embedding tables in one launch:
// blocks [0,512): embWl = emb @ Wl1 ; blocks [512,1024): embWr = emb @ Wr1
__global__ __launch_bounds__(256) void k_embw2(const float* __restrict__ emb,
                                               const float* __restrict__ Wa,
                                               const float* __restrict__ Wb,
                                               float* __restrict__ outa,
                                               float* __restrict__ outb) {
    const int half = blockIdx.x >> 9;
    const float* W = half ? Wb : Wa;
    float* out = half ? outb : outa;
    int idx = (blockIdx.x & 511) * 256 + threadIdx.x;   // 131072 outputs
    int v = idx >> 6, c = idx & 63;
    float s = 0.0f;
#pragma unroll 8
    for (int k = 0; k < 64; k++) s += emb[v * 64 + k] * W[k * 64 + c];
    out[idx] = s;
}

// W2T[n][k] = bf16( k<64 ? Wl2[k][n] : Wr2[k-64][n] ),  [2048][128]
__global__ __launch_bounds__(256) void k_w2t(const float* __restrict__ Wl2,
                                             const float* __restrict__ Wr2,
                                             ushort_t* __restrict__ W2T) {
    __shared__ ushort_t T[64 * 66];
    const int k0 = blockIdx.x * 64;               // 0 or 64
    const int n0 = blockIdx.y * 64;
    const float* Wsrc = (k0 == 0) ? Wl2 : Wr2;
    const int tid = threadIdx.x;
#pragma unroll
    for (int i = 0; i < 16; i++) {
        int idx = i * 256 + tid;
        int k = idx >> 6, n = idx & 63;           // lane -> n : coalesced global read
        T[n * 66 + k] = f2bf(Wsrc[(size_t)k * VOCAB + n0 + n]);
    }
    __syncthreads();
#pragma unroll
    for (int i = 0; i < 16; i++) {
        int idx = i * 256 + tid;
        int n = idx >> 6, k = idx & 63;           // lane -> k : coalesced global write
        W2T[(size_t)(n0 + n) * 128 + k0 + k] = T[n * 66 + k];
    }
}

__global__ __launch_bounds__(256) void k_hist(const int* __restrict__ dst,
                                              int* __restrict__ degi) {
    int e = blockIdx.x * 256 + threadIdx.x;
    if (e < N_EDGES) atomicAdd(&degi[dst[e]], 1);
}

__global__ __launch_bounds__(256) void k_scan1(const int* __restrict__ degi,
                                               int* __restrict__ bsum) {
    int i = blockIdx.x * 256 + threadIdx.x;
    int v = (i < N_NODES) ? degi[i] : 0;
#pragma unroll
    for (int off = 1; off < 64; off <<= 1) v += __shfl_xor(v, off);
    __shared__ int ws[4];
    if ((threadIdx.x & 63) == 0) ws[threadIdx.x >> 6] = v;
    __syncthreads();
    if (threadIdx.x == 0) bsum[blockIdx.x] = ws[0] + ws[1] + ws[2] + ws[3];
}

__global__ __launch_bounds__(512) void k_scan2(const int* __restrict__ bsum,
                                               int* __restrict__ boff,
                                               int* __restrict__ rowptr) {
    __shared__ int s[512];
    int t = threadIdx.x;
    int v = (t < NB_SCAN) ? bsum[t] : 0;
    s[t] = v;
    __syncthreads();
    for (int off = 1; off < 512; off <<= 1) {
        int a = (t >= off) ? s[t - off] : 0;
        __syncthreads();
        s[t] += a;
        __syncthreads();
    }
    if (t < NB_SCAN) boff[t] = s[t] - v;          // exclusive
    if (t == NB_SCAN - 1) rowptr[N_NODES] = s[t]; // total = 1.6M
}

__global__ __launch_bounds__(256) void k_scan3(const int* __restrict__ degi,
                                               const int* __restrict__ boff,
                                               int* __restrict__ rowptr,
                                               int* __restrict__ cursor) {
    __shared__ int s[256];
    int t = threadIdx.x;
    int i = blockIdx.x * 256 + t;
    int v = (i < N_NODES) ? degi[i] : 0;
    s[t] = v;
    __syncthreads();
    for (int off = 1; off < 256; off <<= 1) {
        int a = (t >= off) ? s[t - off] : 0;
        __syncthreads();
        s[t] += a;
        __syncthreads();
    }
    if (i < N_NODES) {
        int ex = boff[blockIdx.x] + s[t] - v;
        rowptr[i] = ex;
        cursor[i] = ex;
    }
}

// one int2 (src, voc) scattered store per edge: half the dirty-line touches
// of the old two-array version (write amplification is per-line, not per-byte)
__global__ __launch_bounds__(256) void k_fill(const int* __restrict__ src,
                                              const int* __restrict__ dst,
                                              const int* __restrict__ x,
                                              int* __restrict__ cursor,
                                              int2* __restrict__ col2) {
    int e = blockIdx.x * 256 + threadIdx.x;
    if (e >= N_EDGES) return;
    int d = dst[e];
    int s = src[e];
    int voc = x[s];
    int pos = atomicAdd(&cursor[d], 1);
    col2[pos] = make_int2(s, voc);
}

// h1[n] = relu( mean_e embWl[voc_e] + embWr[x[n]] + b1 ), one wave per node.
// Edge loop software-pipelined: next col2 entry is in flight while the
// current embWl row loads, so per-iter latency = max(L2,L2) not the sum.
__global__ __launch_bounds__(256) void k_agg1(const int* __restrict__ rowptr,
                                              const int2* __restrict__ col2,
                                              const int* __restrict__ x,
                                              const float* __restrict__ embWl,
                                              const float* __restrict__ embWr,
                                              const float* __restrict__ b1,
                                              float* __restrict__ h1) {
    int gw = (blockIdx.x * 256 + threadIdx.x) >> 6;
    int j = threadIdx.x & 63;
    if (gw >= N_NODES) return;
    int r0 = rowptr[gw], r1 = rowptr[gw + 1];
    float sum = 0.0f;
    if (r0 < r1) {
        int voc = col2[r0].y;
        for (int e = r0 + 1; e < r1; e++) {
            int vnext = col2[e].y;                 // issue before dependent use
            sum += embWl[(voc << 6) + j];
            voc = vnext;
        }
        sum += embWl[(voc << 6) + j];
    }
    float inv = 1.0f / fmaxf((float)(r1 - r0), 1.0f);
    float self = embWr[(x[gw] << 6) + j];
    h1[(gw << 6) + j] = fmaxf(sum * inv + self + b1[j], 0.0f);
}

// X2b[m] = bf16[ mean_e h1[src_e] | h1[mask[m]] ], one wave per masked row
__global__ __launch_bounds__(256) void k_x2(const int* __restrict__ mask,
                                            const int* __restrict__ rowptr,
                                            const int2* __restrict__ col2,
                                            const float* __restrict__ h1,
                                            ushort_t* __restrict__ X2b) {
    int gw = (blockIdx.x * 256 + threadIdx.x) >> 6;
    int j = threadIdx.x & 63;
    if (gw >= N_MASK) return;
    int n = mask[gw];
    int r0 = rowptr[n], r1 = rowptr[n + 1];
    float sum = 0.0f;
    if (r0 < r1) {
        int s = col2[r0].x;
        for (int e = r0 + 1; e < r1; e++) {
            int snext = col2[e].x;
            sum += h1[(s << 6) + j];
            s = snext;
        }
        sum += h1[(s << 6) + j];
    }
    float inv = 1.0f / fmaxf((float)(r1 - r0), 1.0f);
    X2b[gw * 128 + j]      = f2bf(sum * inv);
    X2b[gw * 128 + 64 + j] = f2bf(h1[(n << 6) + j]);
}

// out[R][c] = b2[c] + X2[R] . W2T[c]   via bf16 MFMA, fp32 accumulate.
__global__ __launch_bounds__(256) void k_gemm2_mfma(const ushort_t* __restrict__ X2b,
                                                    const ushort_t* __restrict__ W2T,
                                                    const float* __restrict__ bias,
                                                    float* __restrict__ out,
                                                    int M) {
    __shared__ ushort_t As[64 * 144];
    __shared__ ushort_t Bs[64 * 144];
    const int tid  = threadIdx.x;
    const int row0 = blockIdx.x * 64;
    const int col0 = blockIdx.y * 64;

#pragma unroll
    for (int i = 0; i < 4; i++) {
        int idx = i * 256 + tid;
        int r = idx >> 4, ch = idx & 15;
        int R = row0 + r;
        short8 v = {0, 0, 0, 0, 0, 0, 0, 0};
        if (R < M) v = *(const short8*)(X2b + (size_t)R * 128 + ch * 8);
        *(short8*)(As + r * 144 + ch * 8) = v;
    }
#pragma unroll
    for (int i = 0; i < 4; i++) {
        int idx = i * 256 + tid;
        int r = idx >> 4, ch = idx & 15;
        *(short8*)(Bs + r * 144 + ch * 8) =
            *(const short8*)(W2T + (size_t)(col0 + r) * 128 + ch * 8);
    }
    __syncthreads();

    const int lane = tid & 63;
    const int wv   = tid >> 6;            // 4 waves
    const int wr = wv >> 1, wc = wv & 1;  // 2x2 wave grid of 32x32 quadrants
    const int l15 = lane & 15, q = lane >> 4;

    f32x4 acc[2][2] = {};
    const ushort_t* Abase = As + (wr * 32 + l15) * 144 + q * 8;
    const ushort_t* Bbase = Bs + (wc * 32 + l15) * 144 + q * 8;

#pragma unroll
    for (int ks = 0; ks < 4; ks++) {
        short8 a0 = *(const short8*)(Abase + ks * 32);
        short8 a1 = *(const short8*)(Abase + 16 * 144 + ks * 32);
        short8 b0 = *(const short8*)(Bbase + ks * 32);
        short8 b1 = *(const short8*)(Bbase + 16 * 144 + ks * 32);
        acc[0][0] = __builtin_amdgcn_mfma_f32_16x16x32_bf16(a0, b0, acc[0][0], 0, 0, 0);
        acc[0][1] = __builtin_amdgcn_mfma_f32_16x16x32_bf16(a0, b1, acc[0][1], 0, 0, 0);
        acc[1][0] = __builtin_amdgcn_mfma_f32_16x16x32_bf16(a1, b0, acc[1][0], 0, 0, 0);
        acc[1][1] = __builtin_amdgcn_mfma_f32_16x16x32_bf16(a1, b1, acc[1][1], 0, 0, 0);
    }

    // C/D layout: col = lane&15, row = (lane>>4)*4 + reg  [verified m89/m91]
#pragma unroll
    for (int ni = 0; ni < 2; ni++) {
        int c_ = col0 + wc * 32 + ni * 16 + l15;
        float bv = bias[c_];
#pragma unroll
        for (int mi = 0; mi < 2; mi++) {
#pragma unroll
            for (int reg = 0; reg < 4; reg++) {
                int r_ = row0 + wr * 32 + mi * 16 + q * 4 + reg;
                if (r_ < M) out[(size_t)r_ * VOCAB + c_] = acc[mi][ni][reg] + bv;
            }
        }
    }
}

__global__ __launch_bounds__(256) void k_logsoftmax(float* __restrict__ out) {
    const int row = blockIdx.x;
    float4* p4 = (float4*)(out + (size_t)row * VOCAB);
    const int tid = threadIdx.x;
    float4 v[2];
    float m = -INFINITY;
#pragma unroll
    for (int i = 0; i < 2; i++) {
        v[i] = p4[tid + i * 256];
        m = fmaxf(m, fmaxf(fmaxf(v[i].x, v[i].y), fmaxf(v[i].z, v[i].w)));
    }
#pragma unroll
    for (int off = 1; off < 64; off <<= 1) m = fmaxf(m, __shfl_xor(m, off));
    __shared__ float redm[4];
    __shared__ float reds[4];
    int wave = tid >> 6;
    if ((tid & 63) == 0) redm[wave] = m;
    __syncthreads();
    m = fmaxf(fmaxf(redm[0], redm[1]), fmaxf(redm[2], redm[3]));
    float s = 0.0f;
#pragma unroll
    for (int i = 0; i < 2; i++)
        s += expf(v[i].x - m) + expf(v[i].y - m) + expf(v[i].z - m) + expf(v[i].w - m);
#pragma unroll
    for (int off = 1; off < 64; off <<= 1) s += __shfl_xor(s, off);
    if ((tid & 63) == 0) reds[wave] = s;
    __syncthreads();
    s = reds[0] + reds[1] + reds[2] + reds[3];
    float L = m + logf(s);
#pragma unroll
    for (int i = 0; i < 2; i++) {
        float4 o = v[i];
        o.x -= L; o.y -= L; o.z -= L; o.w -= L;
        p4[tid + i * 256] = o;
    }
}

extern "C" void kernel_launch(void* const* d_in, const int* in_sizes, int n_in,
                              void* d_out, int out_size, void* d_ws, size_t ws_size,
                              hipStream_t stream) {
    const int*   x    = (const int*)d_in[0];
    const int*   ei   = (const int*)d_in[1];
    const int*   src  = ei;
    const int*   dst  = ei + N_EDGES;
    const int*   mask = (const int*)d_in[2];
    const float* emb  = (const float*)d_in[3];
    const float* Wl1  = (const float*)d_in[4];
    const float* bl1  = (const float*)d_in[5];
    const float* Wr1  = (const float*)d_in[6];
    const float* Wl2  = (const float*)d_in[7];
    const float* bl2  = (const float*)d_in[8];
    const float* Wr2  = (const float*)d_in[9];
    float* out = (float*)d_out;

    char* ws = (char*)d_ws;
    float*    h1     = (float*)(ws + H1_OFF);
    ushort_t* X2b    = (ushort_t*)(ws + X2B_OFF);
    ushort_t* W2T    = (ushort_t*)(ws + W2T_OFF);
    float*    embWl  = (float*)(ws + EWL_OFF);
    float*    embWr  = (float*)(ws + EWR_OFF);
    int*      rowptr = (int*)(ws + ROWPTR_OFF);
    int*      cursor = (int*)(ws + CURSOR_OFF);
    int*      degi   = (int*)(ws + DEGI_OFF);
    int*      bsum   = (int*)(ws + BSUM_OFF);
    int*      boff   = (int*)(ws + BOFF_OFF);
    int2*     col2   = (int2*)(ws + COL2_OFF);

    hipMemsetAsync(ws + DEGI_OFF, 0, 400000, stream);   // only degi needs zeros

    // transformed-embedding tables + bf16-transposed layer-2 weights
    k_embw2<<<1024, 256, 0, stream>>>(emb, Wl1, Wr1, embWl, embWr);
    dim3 gw2(2, VOCAB / 64);
    k_w2t<<<gw2, 256, 0, stream>>>(Wl2, Wr2, W2T);

    // CSR by destination
    k_hist <<<(N_EDGES + 255) / 256, 256, 0, stream>>>(dst, degi);
    k_scan1<<<NB_SCAN, 256, 0, stream>>>(degi, bsum);
    k_scan2<<<1, 512, 0, stream>>>(bsum, boff, rowptr);
    k_scan3<<<NB_SCAN, 256, 0, stream>>>(degi, boff, rowptr, cursor);
    k_fill <<<(N_EDGES + 255) / 256, 256, 0, stream>>>(src, dst, x, cursor, col2);

    // layer 1 fused: aggregate transformed embeddings + self + bias + relu
    k_agg1<<<(N_NODES * 64 + 255) / 256, 256, 0, stream>>>(rowptr, col2, x, embWl, embWr, bl1, h1);

    // layer 2: gather masked rows into compact bf16 X2, then MFMA GEMM
    k_x2<<<(N_MASK * 64 + 255) / 256, 256, 0, stream>>>(mask, rowptr, col2, h1, X2b);
    dim3 g2((N_MASK + 63) / 64, VOCAB / 64);
    k_gemm2_mfma<<<g2, 256, 0, stream>>>(X2b, W2T, bl2, out, N_MASK);

    k_logsoftmax<<<N_MASK, 256, 0, stream>>>(out);
}